// Round 9
// baseline (46.947 us; speedup 1.0000x reference)
//
#include <hip/hip_runtime.h>
#include <stdint.h>

#define HW   4096      // 64*64 spatial per batch
#define NEMB 1024

typedef float        f32x4  __attribute__((ext_vector_type(4)));
typedef short        h16x8  __attribute__((ext_vector_type(8)));
typedef unsigned int u32x4  __attribute__((ext_vector_type(4)));

// pack 2 fp32 -> 2 fp16 (round-toward-zero) in one u32 (lo = first operand)
#define CVTPKH(D, LO, HI) asm("v_cvt_pkrtz_f16_f32 %0, %1, %2" : "=v"(D) : "v"(LO), "v"(HI))

// direct global->LDS DMA, 16B per lane
__device__ __forceinline__ void gload_lds16(const float* g, float* l) {
    __builtin_amdgcn_global_load_lds(
        (const __attribute__((address_space(1))) void*)(uintptr_t)g,
        (__attribute__((address_space(3))) void*)(uintptr_t)l, 16, 0, 0);
}

// ---------------- init: counts/errsum, ens[k]=||e_k||^2, swizzled f16 codebook ----
// embw layout: u32[1024][8 slots], slot s of row k holds 16B chunk (s ^ (k&7)),
// chunk c = e[c*8 .. c*8+7] packed as 4 u32 pairs -> matches et LDS layout linearly.
__global__ __launch_bounds__(128) void vq_init(const float* __restrict__ emb,
                                               unsigned int* __restrict__ counts,
                                               float* __restrict__ errsum,
                                               float* __restrict__ ens,
                                               unsigned int* __restrict__ embw) {
    const int k = blockIdx.x * 128 + threadIdx.x;
    counts[k] = 0u;
    if (k == 0) *errsum = 0.0f;
    const float* e = emb + k * 64;
    float a[8] = {0,0,0,0,0,0,0,0};
    unsigned int* dst = embw + k * 32;
    #pragma unroll
    for (int c = 0; c < 8; ++c) {
        f32x4 v0 = *(const f32x4*)(e + c * 8);
        f32x4 v1 = *(const f32x4*)(e + c * 8 + 4);
        a[0] += v0.x * v0.x; a[1] += v0.y * v0.y;
        a[2] += v0.z * v0.z; a[3] += v0.w * v0.w;
        a[4] += v1.x * v1.x; a[5] += v1.y * v1.y;
        a[6] += v1.z * v1.z; a[7] += v1.w * v1.w;
        u32x4 w;
        CVTPKH(w.x, v0.x, v0.y); CVTPKH(w.y, v0.z, v0.w);
        CVTPKH(w.z, v1.x, v1.y); CVTPKH(w.w, v1.z, v1.w);
        *(u32x4*)&dst[(c ^ (k & 7)) << 2] = w;
    }
    ens[k] = ((a[0]+a[1]) + (a[2]+a[3])) + ((a[4]+a[5]) + (a[6]+a[7]));
}

// ---------------- main: f16 MFMA distance screen + exact fused argmin -------------
// grid 512 x 512 (2 blocks/CU, 16 waves/CU). Block: 128 samples.
// Wave: 16 samples x all 1024 embs (4 k-tiles of 256, DMA'd from embw).
__global__ __launch_bounds__(512, 4)
void vq_main(const float* __restrict__ z, const float* __restrict__ emb,
             const float* __restrict__ ens, const unsigned int* __restrict__ embw,
             float* __restrict__ out, unsigned int* __restrict__ counts,
             float* __restrict__ errsum)
{
    __shared__ __attribute__((aligned(16))) float z_lds[64 * 128];       // fp32 [d][x]
    __shared__ __attribute__((aligned(16))) unsigned int et_w[256 * 32]; // f16 tile (swizzled)
    __shared__ __attribute__((aligned(16))) float ens_lds[NEMB];
    __shared__ int   idx_sh[128];
    __shared__ float errp[512];

    const int t   = threadIdx.x;
    const int n0  = blockIdx.x * 128;
    const int bb  = n0 >> 12;
    const int hw0 = n0 & 4095;
    const float* zb = z + bb * (64 * HW) + hw0;

    // ---- DMA z tile fp32 [d][128] ----
    #pragma unroll
    for (int it = 0; it < 4; ++it) {
        const int p = it * 512 + t;            // 16B chunk 0..2047
        gload_lds16(zb + (p >> 5) * HW + (p & 31) * 4, z_lds + p * 4);
    }
    // ---- DMA ens (4KB) ----
    if (t < 256) gload_lds16(ens + t * 4, ens_lds + t * 4);
    // ---- DMA et tile 0 (32KB, linear from pre-swizzled embw) ----
    #pragma unroll
    for (int it = 0; it < 4; ++it) {
        const int p = it * 512 + t;            // 16B chunk 0..2047
        gload_lds16((const float*)embw + p * 4, (float*)et_w + p * 4);
    }
    __syncthreads();   // all DMA drained

    const int l   = t & 63;     // lane
    const int wv  = t >> 6;     // wave 0..7 -> samples wv*16..wv*16+15
    const int col = l & 15;     // A row selector (input) / C col = emb idx (output)
    const int bg  = l >> 4;     // k-group

    // ---- A fragments: z f16 (RTZ), row=col, k = 8*bg + e (same pack rule as B) ----
    h16x8 a0, a1;
    {
        const int xs = wv * 16 + col;
        u32x4 wa, wb;
        #pragma unroll
        for (int p2 = 0; p2 < 4; ++p2) {
            float lo = z_lds[(bg * 8 + p2 * 2    ) * 128 + xs];
            float hi = z_lds[(bg * 8 + p2 * 2 + 1) * 128 + xs];
            CVTPKH(wa[p2], lo, hi);
            float lo2 = z_lds[(32 + bg * 8 + p2 * 2    ) * 128 + xs];
            float hi2 = z_lds[(32 + bg * 8 + p2 * 2 + 1) * 128 + xs];
            CVTPKH(wb[p2], lo2, hi2);
        }
        a0 = __builtin_bit_cast(h16x8, wa);
        a1 = __builtin_bit_cast(h16x8, wb);
    }

    const int slot0 = bg ^ (col & 7);
    const unsigned int* ep0 = et_w + col * 32 + slot0 * 4;
    const unsigned int* ep1 = et_w + col * 32 + (slot0 ^ 4) * 4;
    const float* ensp = ens_lds + col;

    float mval[4] = {__builtin_inff(), __builtin_inff(), __builtin_inff(), __builtin_inff()};
    int   midx[4] = {0, 0, 0, 0};

    #pragma unroll
    for (int kt = 0; kt < 4; ++kt) {
        #pragma unroll
        for (int i = 0; i < 16; ++i) {
            u32x4 bw0 = *(const u32x4*)(ep0 + i * 512);
            u32x4 bw1 = *(const u32x4*)(ep1 + i * 512);
            float en = ensp[kt * 256 + i * 16];
            f32x4 cc = {0.0f, 0.0f, 0.0f, 0.0f};
            cc = __builtin_amdgcn_mfma_f32_16x16x32_f16(a0, __builtin_bit_cast(h16x8, bw0), cc, 0, 0, 0);
            cc = __builtin_amdgcn_mfma_f32_16x16x32_f16(a1, __builtin_bit_cast(h16x8, bw1), cc, 0, 0, 0);
            const int kg = kt * 256 + i * 16 + col;
            #pragma unroll
            for (int j = 0; j < 4; ++j) {
                const float s = fmaf(-2.0f, cc[j], en);   // ||e||^2 - 2 z.e
                if (s < mval[j]) { mval[j] = s; midx[j] = kg; }  // ascending k => first-idx ties
            }
        }

        __syncthreads();   // all waves done reading et[kt]
        if (kt < 3) {      // DMA next tile (linear source, zero VGPR cost)
            const float* src = (const float*)(embw + (kt + 1) * 8192);
            #pragma unroll
            for (int it = 0; it < 4; ++it) {
                const int p = it * 512 + t;
                gload_lds16(src + p * 4, (float*)et_w + p * 4);
            }
            __syncthreads();   // vmcnt drained -> et[kt+1] ready
        }
    }

    // ---- exact cross-lane argmin across the 16 cols (tie-break: smaller k) ----
    #pragma unroll
    for (int j = 0; j < 4; ++j) {
        float m = mval[j]; int id = midx[j];
        #pragma unroll
        for (int mk = 1; mk <= 8; mk <<= 1) {
            float m2 = __shfl_xor(m, mk, 64);
            int   i2 = __shfl_xor(id, mk, 64);
            if (m2 < m || (m2 == m && i2 < id)) { m = m2; id = i2; }
        }
        if (col == 0) idx_sh[wv * 16 + bg * 4 + j] = id;   // C row = 4*bg + j
    }
    __syncthreads();

    // ---- histogram ----
    if (t < 128) atomicAdd(&counts[idx_sh[t]], 1u);

    // ---- epilogue: out = z + (e - z) in exact ref fp32 order; exact error sum ----
    {
        const int x  = t & 127;
        const int cg = t >> 7;     // 0..3 -> channels cg*16..+15
        const int idx = idx_sh[x];
        const float* er = emb + idx * 64;
        float* ob = out + bb * (64 * HW) + hw0 + x;
        float part = 0.0f;
        #pragma unroll
        for (int cq = 0; cq < 4; ++cq) {
            const int c = cg * 16 + cq * 4;
            f32x4 e4 = *(const f32x4*)&er[c];
            float z0 = z_lds[(c+0) * 128 + x];
            float z1 = z_lds[(c+1) * 128 + x];
            float z2 = z_lds[(c+2) * 128 + x];
            float z3 = z_lds[(c+3) * 128 + x];
            ob[(c+0) * HW] = z0 + (e4.x - z0);
            ob[(c+1) * HW] = z1 + (e4.y - z1);
            ob[(c+2) * HW] = z2 + (e4.z - z2);
            ob[(c+3) * HW] = z3 + (e4.w - z3);
            float d0 = z0 - e4.x, d1 = z1 - e4.y, d2 = z2 - e4.z, d3 = z3 - e4.w;
            part = fmaf(d0, d0, part); part = fmaf(d1, d1, part);
            part = fmaf(d2, d2, part); part = fmaf(d3, d3, part);
        }
        errp[t] = part;
    }
    __syncthreads();
    if (t < 128) {
        float s = (errp[t] + errp[t + 128]) + (errp[t + 256] + errp[t + 384]);
        #pragma unroll
        for (int off = 32; off >= 1; off >>= 1) s += __shfl_down(s, off, 64);
        if ((t & 63) == 0) atomicAdd(errsum, s);
    }
}

// ---------------- finalize: scalars ----------------
__global__ __launch_bounds__(256) void vq_fin(const unsigned int* __restrict__ counts,
                                              const float* __restrict__ errsum,
                                              float* __restrict__ scal)
{
    __shared__ float part[4];
    const int t = threadIdx.x;
    float s = 0.0f;
    for (int k = t; k < NEMB; k += 256) {
        float p = (float)counts[k] * (1.0f / 65536.0f);
        s += p * logf(p + 1e-10f);
    }
    #pragma unroll
    for (int off = 32; off >= 1; off >>= 1) s += __shfl_down(s, off, 64);
    if ((t & 63) == 0) part[t >> 6] = s;
    __syncthreads();
    if (t == 0) {
        float tot = (part[0] + part[1]) + (part[2] + part[3]);
        float es  = *errsum;
        scal[0] = 1.25f * (es * (1.0f / 4194304.0f));  // loss = 1.25 * mse
        scal[1] = expf(-tot);                          // perplexity
        scal[2] = es * (1.0f / 65536.0f);              // avg_error
    }
}

extern "C" void kernel_launch(void* const* d_in, const int* in_sizes, int n_in,
                              void* d_out, int out_size, void* d_ws, size_t ws_size,
                              hipStream_t stream) {
    const float* z   = (const float*)d_in[0];
    const float* emb = (const float*)d_in[1];
    float* out = (float*)d_out;
    unsigned int* counts = (unsigned int*)d_ws;
    float* errsum = (float*)((char*)d_ws + 4096);
    float* ens    = (float*)((char*)d_ws + 8192);
    unsigned int* embw = (unsigned int*)((char*)d_ws + 16384);

    vq_init<<<8, 128, 0, stream>>>(emb, counts, errsum, ens, embw);
    vq_main<<<512, 512, 0, stream>>>(z, emb, ens, embw, out, counts, errsum);
    vq_fin<<<1, 256, 0, stream>>>(counts, errsum, out + 4194304);
}

// Round 10
// 44.128 us; speedup vs baseline: 1.0639x; 1.0639x over previous
//
#include <hip/hip_runtime.h>
#include <stdint.h>

#define HW   4096      // 64*64 spatial per batch
#define NEMB 1024

typedef float        f32x4  __attribute__((ext_vector_type(4)));
typedef short        h16x8  __attribute__((ext_vector_type(8)));
typedef unsigned int u32x4  __attribute__((ext_vector_type(4)));

// pack 2 fp32 -> 2 fp16 (RTZ) in one u32 (lo = first operand)
#define CVTPKH(D, LO, HI) asm("v_cvt_pkrtz_f16_f32 %0, %1, %2" : "=v"(D) : "v"(LO), "v"(HI))

// direct global->LDS DMA, 16B per lane (lane-linear dest only!)
__device__ __forceinline__ void gload_lds16(const float* g, float* l) {
    __builtin_amdgcn_global_load_lds(
        (const __attribute__((address_space(1))) void*)(uintptr_t)g,
        (__attribute__((address_space(3))) void*)(uintptr_t)l, 16, 0, 0);
}

// ---------------- init: counts/errsum, ens1[k]=1+||e_k||^2, f16 codebook -----------
// embh: u32[1024][32] row-major; u32 4c+p of row k = f16 pair (e[8c+2p], e[8c+2p+1]).
__global__ __launch_bounds__(128) void vq_init(const float* __restrict__ emb,
                                               unsigned int* __restrict__ counts,
                                               float* __restrict__ errsum,
                                               float* __restrict__ ens1,
                                               unsigned int* __restrict__ embh) {
    const int k = blockIdx.x * 128 + threadIdx.x;
    counts[k] = 0u;
    if (k == 0) *errsum = 0.0f;
    const float* e = emb + k * 64;
    unsigned int* dst = embh + k * 32;
    float a[8] = {0,0,0,0,0,0,0,0};
    #pragma unroll
    for (int c = 0; c < 8; ++c) {
        f32x4 v0 = *(const f32x4*)(e + c * 8);
        f32x4 v1 = *(const f32x4*)(e + c * 8 + 4);
        a[0] += v0.x * v0.x; a[1] += v0.y * v0.y;
        a[2] += v0.z * v0.z; a[3] += v0.w * v0.w;
        a[4] += v1.x * v1.x; a[5] += v1.y * v1.y;
        a[6] += v1.z * v1.z; a[7] += v1.w * v1.w;
        u32x4 w;
        CVTPKH(w.x, v0.x, v0.y); CVTPKH(w.y, v0.z, v0.w);
        CVTPKH(w.z, v1.x, v1.y); CVTPKH(w.w, v1.z, v1.w);
        *(u32x4*)&dst[c * 4] = w;
    }
    ens1[k] = 1.0f + (((a[0]+a[1]) + (a[2]+a[3])) + ((a[4]+a[5]) + (a[6]+a[7])));
}

// ---------------- main: B-persistent MFMA screen, barrier-free inner loop ----------
// grid 512 x 512 (2 blocks/CU). Block: 128 samples. Wave w: embs w*128..w*128+127
// (16 B-frags in VGPRs), loops 8 sample-tiles of 16 (A-frags from packed f16 LDS).
__global__ __launch_bounds__(512, 4)
void vq_main(const float* __restrict__ z, const float* __restrict__ emb,
             const float* __restrict__ ens1, const unsigned int* __restrict__ embh,
             float* __restrict__ out, unsigned int* __restrict__ counts,
             float* __restrict__ errsum)
{
    __shared__ __attribute__((aligned(16))) float z_lds[64 * 128];   // fp32 [d][x]
    __shared__ __attribute__((aligned(16))) unsigned int zh[128 * 32]; // f16 pairs [x][slot]
    __shared__ __attribute__((aligned(16))) float ens_lds[NEMB];
    __shared__ unsigned int kd[8][128];
    __shared__ int   idx_sh[128];
    __shared__ float errp[512];

    const int t   = threadIdx.x;
    const int n0  = blockIdx.x * 128;
    const int bb  = n0 >> 12;
    const int hw0 = n0 & 4095;
    const float* zb = z + bb * (64 * HW) + hw0;

    // ---- DMA z tile fp32 [d][128] + ens1 ----
    #pragma unroll
    for (int it = 0; it < 4; ++it) {
        const int p = it * 512 + t;
        gload_lds16(zb + (p >> 5) * HW + (p & 31) * 4, z_lds + p * 4);
    }
    if (t < 256) gload_lds16(ens1 + t * 4, ens_lds + t * 4);
    __syncthreads();   // z_lds + ens_lds ready

    // ---- build zh: f16-packed z, slot-swizzled. slot s of row x holds chunk s^(x&7)
    {
        const int x = t & 127;
        #pragma unroll
        for (int ss = 0; ss < 2; ++ss) {
            const int s = (x + (t >> 7) * 2 + ss) & 7;   // stagger slots across lanes
            const int c = s ^ (x & 7);
            u32x4 w;
            CVTPKH(w.x, z_lds[(8*c + 0) * 128 + x], z_lds[(8*c + 1) * 128 + x]);
            CVTPKH(w.y, z_lds[(8*c + 2) * 128 + x], z_lds[(8*c + 3) * 128 + x]);
            CVTPKH(w.z, z_lds[(8*c + 4) * 128 + x], z_lds[(8*c + 5) * 128 + x]);
            CVTPKH(w.w, z_lds[(8*c + 6) * 128 + x], z_lds[(8*c + 7) * 128 + x]);
            *(u32x4*)&zh[x * 32 + s * 4] = w;
        }
    }

    const int l   = t & 63;
    const int wv  = t >> 6;     // wave owns embs wv*128..wv*128+127
    const int col = l & 15;
    const int bg  = l >> 4;

    // ---- persistent B-frags (16 x u32x4 = 64 VGPR) + en1 regs ----
    u32x4 bw0[8], bw1[8];
    {
        const unsigned int* ebase = embh + (wv * 128 + col) * 32 + bg * 4;
        #pragma unroll
        for (int g = 0; g < 8; ++g) {
            bw0[g] = *(const u32x4*)(ebase + g * 16 * 32);
            bw1[g] = *(const u32x4*)(ebase + g * 16 * 32 + 16);
        }
    }
    float en[8];
    #pragma unroll
    for (int g = 0; g < 8; ++g) en[g] = ens_lds[wv * 128 + g * 16 + col];

    __syncthreads();   // zh ready

    // ---- main loop: 8 sample-tiles, no barriers ----
    const unsigned int lkc = (unsigned int)col;
    #pragma unroll 1
    for (int st = 0; st < 8; ++st) {
        const int xs = st * 16 + col;
        const int sA = bg ^ (col & 7);
        u32x4 wa = *(const u32x4*)&zh[xs * 32 + sA * 4];
        u32x4 wb = *(const u32x4*)&zh[xs * 32 + (sA ^ 4) * 4];
        h16x8 a0 = __builtin_bit_cast(h16x8, wa);
        h16x8 a1 = __builtin_bit_cast(h16x8, wb);

        unsigned int k0 = ~0u, k1 = ~0u, k2 = ~0u, k3 = ~0u;
        #pragma unroll
        for (int g = 0; g < 8; ++g) {
            f32x4 cc = {0.0f, 0.0f, 0.0f, 0.0f};
            cc = __builtin_amdgcn_mfma_f32_16x16x32_f16(a0, __builtin_bit_cast(h16x8, bw0[g]), cc, 0, 0, 0);
            cc = __builtin_amdgcn_mfma_f32_16x16x32_f16(a1, __builtin_bit_cast(h16x8, bw1[g]), cc, 0, 0, 0);
            const unsigned int lk = (unsigned int)(g << 4) | lkc;
            float s0 = fmaf(-2.0f, cc[0], en[g]);
            float s1 = fmaf(-2.0f, cc[1], en[g]);
            float s2 = fmaf(-2.0f, cc[2], en[g]);
            float s3 = fmaf(-2.0f, cc[3], en[g]);
            unsigned int q0 = (__builtin_bit_cast(unsigned int, s0) & ~127u) | lk;
            unsigned int q1 = (__builtin_bit_cast(unsigned int, s1) & ~127u) | lk;
            unsigned int q2 = (__builtin_bit_cast(unsigned int, s2) & ~127u) | lk;
            unsigned int q3 = (__builtin_bit_cast(unsigned int, s3) & ~127u) | lk;
            k0 = k0 < q0 ? k0 : q0;  k1 = k1 < q1 ? k1 : q1;
            k2 = k2 < q2 ? k2 : q2;  k3 = k3 < q3 ? k3 : q3;
        }
        // reduce across the 16 cols (keys carry within-wave k -> exact first-index)
        #pragma unroll
        for (int mk = 1; mk <= 8; mk <<= 1) {
            unsigned int o0 = (unsigned int)__shfl_xor((int)k0, mk, 64);
            unsigned int o1 = (unsigned int)__shfl_xor((int)k1, mk, 64);
            unsigned int o2 = (unsigned int)__shfl_xor((int)k2, mk, 64);
            unsigned int o3 = (unsigned int)__shfl_xor((int)k3, mk, 64);
            k0 = k0 < o0 ? k0 : o0;  k1 = k1 < o1 ? k1 : o1;
            k2 = k2 < o2 ? k2 : o2;  k3 = k3 < o3 ? k3 : o3;
        }
        if (col == 0) {   // 4 lanes/wave write their 4 samples (C rows 4bg+j)
            u32x4 kv = {k0, k1, k2, k3};
            *(u32x4*)&kd[wv][st * 16 + bg * 4] = kv;
        }
    }
    __syncthreads();

    // ---- exact cross-wave argmin (8 candidates per sample) + histogram ----
    if (t < 128) {
        unsigned int kw = kd[0][t];
        unsigned int bv = kw & ~127u;
        int bk = (int)(kw & 127u);
        #pragma unroll
        for (int w = 1; w < 8; ++w) {
            kw = kd[w][t];
            unsigned int vw = kw & ~127u;
            int kk = w * 128 + (int)(kw & 127u);
            if (vw < bv || (vw == bv && kk < bk)) { bv = vw; bk = kk; }
        }
        idx_sh[t] = bk;
        atomicAdd(&counts[bk], 1u);
    }
    __syncthreads();

    // ---- epilogue: out = z + (e - z) in exact ref fp32 order; exact error sum ----
    {
        const int x  = t & 127;
        const int cg = t >> 7;     // 0..3 -> channels cg*16..+15
        const int idx = idx_sh[x];
        const float* er = emb + idx * 64;
        float* ob = out + bb * (64 * HW) + hw0 + x;
        float part = 0.0f;
        #pragma unroll
        for (int cq = 0; cq < 4; ++cq) {
            const int c = cg * 16 + cq * 4;
            f32x4 e4 = *(const f32x4*)&er[c];
            float z0 = z_lds[(c+0) * 128 + x];
            float z1 = z_lds[(c+1) * 128 + x];
            float z2 = z_lds[(c+2) * 128 + x];
            float z3 = z_lds[(c+3) * 128 + x];
            ob[(c+0) * HW] = z0 + (e4.x - z0);
            ob[(c+1) * HW] = z1 + (e4.y - z1);
            ob[(c+2) * HW] = z2 + (e4.z - z2);
            ob[(c+3) * HW] = z3 + (e4.w - z3);
            float d0 = z0 - e4.x, d1 = z1 - e4.y, d2 = z2 - e4.z, d3 = z3 - e4.w;
            part = fmaf(d0, d0, part); part = fmaf(d1, d1, part);
            part = fmaf(d2, d2, part); part = fmaf(d3, d3, part);
        }
        errp[t] = part;
    }
    __syncthreads();
    if (t < 128) {
        float s = (errp[t] + errp[t + 128]) + (errp[t + 256] + errp[t + 384]);
        #pragma unroll
        for (int off = 32; off >= 1; off >>= 1) s += __shfl_down(s, off, 64);
        if ((t & 63) == 0) atomicAdd(errsum, s);
    }
}

// ---------------- finalize: scalars ----------------
__global__ __launch_bounds__(256) void vq_fin(const unsigned int* __restrict__ counts,
                                              const float* __restrict__ errsum,
                                              float* __restrict__ scal)
{
    __shared__ float part[4];
    const int t = threadIdx.x;
    float s = 0.0f;
    for (int k = t; k < NEMB; k += 256) {
        float p = (float)counts[k] * (1.0f / 65536.0f);
        s += p * logf(p + 1e-10f);
    }
    #pragma unroll
    for (int off = 32; off >= 1; off >>= 1) s += __shfl_down(s, off, 64);
    if ((t & 63) == 0) part[t >> 6] = s;
    __syncthreads();
    if (t == 0) {
        float tot = (part[0] + part[1]) + (part[2] + part[3]);
        float es  = *errsum;
        scal[0] = 1.25f * (es * (1.0f / 4194304.0f));  // loss = 1.25 * mse
        scal[1] = expf(-tot);                          // perplexity
        scal[2] = es * (1.0f / 65536.0f);              // avg_error
    }
}

extern "C" void kernel_launch(void* const* d_in, const int* in_sizes, int n_in,
                              void* d_out, int out_size, void* d_ws, size_t ws_size,
                              hipStream_t stream) {
    const float* z   = (const float*)d_in[0];
    const float* emb = (const float*)d_in[1];
    float* out = (float*)d_out;
    unsigned int* counts = (unsigned int*)d_ws;
    float* errsum = (float*)((char*)d_ws + 4096);
    float* ens1   = (float*)((char*)d_ws + 8192);
    unsigned int* embh = (unsigned int*)((char*)d_ws + 16384);

    vq_init<<<8, 128, 0, stream>>>(emb, counts, errsum, ens1, embh);
    vq_main<<<512, 512, 0, stream>>>(z, emb, ens1, embh, out, counts, errsum);
    vq_fin<<<1, 256, 0, stream>>>(counts, errsum, out + 4194304);
}